// Round 4
// baseline (329.706 us; speedup 1.0000x reference)
//
#include <hip/hip_runtime.h>

// Problem constants
#define CIN   128
#define COUT  128
#define DD    36
#define HW    5184
#define DHW   186624          // 36*5184 ; attn per-channel plane is L*81 = same
#define PATCH 9
#define NPW   576             // patches per d-slab (HW/9)
#define L_TOT 2304            // 4 * 576
#define PP    81
#define LDSK  136             // padded k stride (128 + 8) in bf16 elems

typedef __attribute__((ext_vector_type(8))) short bf16x8;
typedef __attribute__((ext_vector_type(4))) float f32x4;

__device__ __forceinline__ short f2bf(float f) {
    unsigned u = __builtin_bit_cast(unsigned, f);
    unsigned r = (u + 0x7fffu + ((u >> 16) & 1u)) >> 16;
    return (short)r;
}

// ---------------------------------------------------------------------------
// Kernel 1: nonzero counts via wave ballots (unchanged; ~25us, near floor).
// Streams the 95.6 MB attn tensor coalesced and warms L3 for kernel 2.
// ---------------------------------------------------------------------------
__global__ __launch_bounds__(256) void count_ballot(
    const float* __restrict__ attn, float* __restrict__ inv)
{
    const int wv   = threadIdx.x >> 6;
    const int lane = threadIdx.x & 63;
    const int w    = blockIdx.x * 4 + wv;      // wave id 0..18431

    const unsigned long long P0X = (1ull << 21) - 1;
    const unsigned long long P0Y = (1ull << 20) - 1;
    const unsigned long long P1X = ((1ull << 20) - 1) << 21;
    const unsigned long long P1Y = ((1ull << 21) - 1) << 20;
    const unsigned long long P1Z = ((1ull << 20) - 1) << 20;
    const unsigned long long P2X = ((1ull << 20) - 1) << 41;
    const unsigned long long P2Z = ((1ull << 21) - 1) << 40;
    const unsigned long long P2W = ((1ull << 20) - 1) << 40;
    const unsigned long long P3X = 0x7ull << 61;
    const unsigned long long P3W = 0xFull << 60;
    const unsigned long long TL  = (1ull << 17) - 1;

    #pragma unroll
    for (int k = 0; k < 4; ++k) {
        const int g = w * 4 + k;               // 4-patch group 0..73727
        const float4* ap = (const float4*)attn + (size_t)g * 81;
        const float4 va = ap[lane];
        float4 vb = (float4){0.f, 0.f, 0.f, 0.f};
        if (lane < 17) vb = ap[64 + lane];

        const unsigned long long bx = __ballot(va.x != 0.f);
        const unsigned long long by = __ballot(va.y != 0.f);
        const unsigned long long bz = __ballot(va.z != 0.f);
        const unsigned long long bw = __ballot(va.w != 0.f);
        const unsigned long long tx = __ballot(vb.x != 0.f);
        const unsigned long long ty = __ballot(vb.y != 0.f);
        const unsigned long long tz = __ballot(vb.z != 0.f);
        const unsigned long long tw = __ballot(vb.w != 0.f);

        const int c0 = __popcll(bx & P0X) + __popcll(by & P0Y)
                     + __popcll(bz & P0Y) + __popcll(bw & P0Y);
        const int c1 = __popcll(bx & P1X) + __popcll(by & P1Y)
                     + __popcll(bz & P1Z) + __popcll(bw & P1Z);
        const int c2 = __popcll(bx & P2X) + __popcll(by & P2X)
                     + __popcll(bz & P2Z) + __popcll(bw & P2W);
        const int c3 = __popcll(bx & P3X) + __popcll(by & P3X)
                     + __popcll(bz & P3X) + __popcll(bw & P3W)
                     + __popcll(tx & TL) + __popcll(ty & TL)
                     + __popcll(tz & TL) + __popcll(tw & TL);

        if (lane < 4) {
            const int cc = (lane == 0) ? c0 : (lane == 1) ? c1
                         : (lane == 2) ? c2 : c3;
            inv[(size_t)g * 4 + lane] = 1.0f / ((float)cc + 1e-5f);
        }
    }
}

// ---------------------------------------------------------------------------
// Kernel 2: persistent pipelined fused conv+attention.
// Each block owns 3 consecutive d (same hwblk, same pd -> same l-set):
// grid = 972 = 3.8 blocks/CU -> ONE co-resident generation (rounds 0-3 ran
// 2.85 phase-locked generations at ~40us each: pure exposed latency).
// Per-block pipeline: reg-prefetch x(d+1) || GEMM(d) + epilogue(d), then
// convert->LDS buf^1, one barrier per tile.  attn epilogue reads for the 3
// tiles hit the same cache lines (kk +-9 within a 324B row) -> L1/L2 after
// L3 warm-up by count_ballot.  inv staged to LDS once per block.
// ---------------------------------------------------------------------------
__global__ __launch_bounds__(256, 4) void fused_pipe(
    const float* __restrict__ x,     // [128][36][5184]
    const float* __restrict__ attn,  // [128][2304][81]
    const float* __restrict__ W,     // [128][128]
    const float* __restrict__ bia,   // [128]
    const float* __restrict__ inv,   // [128][2304]
    float* __restrict__ out)         // [128][36][5184]
{
    __shared__ __align__(16) short xs[2][64][LDSK];   // 34816 B
    __shared__ float inv_s[128][8];                   //  4096 B

    const int t    = threadIdx.x;
    const int wv   = t >> 6;
    const int lane = t & 63;
    const int col  = lane & 15;
    const int quad = lane >> 4;

    const int b      = blockIdx.x;            // 0..971
    const int w0     = b * 3;
    const int hwblk  = w0 / 36;               // 0..80
    const int d0     = w0 - hwblk * 36;       // multiple of 3
    const int hwbase = hwblk * 64;
    const int pd     = d0 / 9;
    const int lbase  = pd * NPW;
    const int ii0    = d0 - pd * 9;           // 0,3,6 (+k stays within patch row set)
    const int p0     = hwbase / 9;            // 8 patches q=0..7 touched

    // ---- stage inv tile once (shared by all 3 d-tiles) ----
    #pragma unroll
    for (int kk = 0; kk < 4; ++kk) {
        const int e = t + 256 * kk;           // 0..1023
        const int c = e >> 3, q = e & 7;
        inv_s[c][q] = inv[(size_t)c * L_TOT + lbase + p0 + q];
    }

    // prefetch register file: 4 stage-units per thread (2 halves of 2)
    float4 pva[4], pvb[4];

#define ISSUE(IT, D) { \
        const int e_ = t + 256 * (IT); \
        const int rp_ = e_ >> 4, f4_ = e_ & 15; \
        const float* xp_ = x + (size_t)(rp_ * 2) * DHW + (size_t)(D) * HW \
                         + hwbase + f4_ * 4; \
        pva[IT] = *(const float4*)xp_; \
        pvb[IT] = *(const float4*)(xp_ + DHW); }

#define WRITE(IT, BUF) { \
        const int e_ = t + 256 * (IT); \
        const int rp_ = e_ >> 4, f4_ = e_ & 15; \
        const int row_ = rp_ * 2, n0_ = f4_ * 4; \
        const float4 va_ = pva[IT], vb_ = pvb[IT]; \
        *(unsigned*)&xs[BUF][n0_ + 0][row_] = \
            (unsigned)(unsigned short)f2bf(va_.x) | ((unsigned)(unsigned short)f2bf(vb_.x) << 16); \
        *(unsigned*)&xs[BUF][n0_ + 1][row_] = \
            (unsigned)(unsigned short)f2bf(va_.y) | ((unsigned)(unsigned short)f2bf(vb_.y) << 16); \
        *(unsigned*)&xs[BUF][n0_ + 2][row_] = \
            (unsigned)(unsigned short)f2bf(va_.z) | ((unsigned)(unsigned short)f2bf(vb_.z) << 16); \
        *(unsigned*)&xs[BUF][n0_ + 3][row_] = \
            (unsigned)(unsigned short)f2bf(va_.w) | ((unsigned)(unsigned short)f2bf(vb_.w) << 16); }

    // ---- prologue: stage tile 0 ----
    ISSUE(0, d0) ISSUE(1, d0) ISSUE(2, d0) ISSUE(3, d0)

    // ---- A fragments + bias (while tile-0 loads are in flight) ----
    const int wbase = wv * 32;
    bf16x8 afrag[2][4];
    #pragma unroll
    for (int mt = 0; mt < 2; ++mt) {
        const int m = wbase + mt * 16 + col;
        #pragma unroll
        for (int s = 0; s < 4; ++s) {
            const float4* wp4 = (const float4*)(W + m * 128 + s * 32 + quad * 8);
            float4 w0v = wp4[0], w1v = wp4[1];
            bf16x8 f;
            f[0] = f2bf(w0v.x); f[1] = f2bf(w0v.y); f[2] = f2bf(w0v.z); f[3] = f2bf(w0v.w);
            f[4] = f2bf(w1v.x); f[5] = f2bf(w1v.y); f[6] = f2bf(w1v.z); f[7] = f2bf(w1v.w);
            afrag[mt][s] = f;
        }
    }
    float bias[2][4];
    #pragma unroll
    for (int mt = 0; mt < 2; ++mt)
        #pragma unroll
        for (int r = 0; r < 4; ++r)
            bias[mt][r] = bia[wbase + mt * 16 + quad * 4 + r];

    WRITE(0, 0) WRITE(1, 0) WRITE(2, 0) WRITE(3, 0)
    __syncthreads();

    // ---- 3 pipelined tiles ----
    #pragma unroll
    for (int k = 0; k < 3; ++k) {
        const int cb = k & 1, nb = cb ^ 1;
        const int d  = d0 + k;
        const int ii = ii0 + k;

        // issue first prefetch half for tile k+1 (covers GEMM + epilogue)
        if (k < 2) { ISSUE(0, d + 1) ISSUE(1, d + 1) }

        // GEMM: 128(Cout) x 64(n) x 128(K), 16x16x32 MFMA
        f32x4 acc[2][4];
        #pragma unroll
        for (int mt = 0; mt < 2; ++mt)
            #pragma unroll
            for (int tt = 0; tt < 4; ++tt)
                acc[mt][tt] = (f32x4){0.f, 0.f, 0.f, 0.f};

        #pragma unroll
        for (int s = 0; s < 4; ++s) {
            bf16x8 bfrag[4];
            #pragma unroll
            for (int tt = 0; tt < 4; ++tt)
                bfrag[tt] = *(const bf16x8*)&xs[cb][tt * 16 + col][s * 32 + quad * 8];
            #pragma unroll
            for (int mt = 0; mt < 2; ++mt)
                #pragma unroll
                for (int tt = 0; tt < 4; ++tt)
                    acc[mt][tt] = __builtin_amdgcn_mfma_f32_16x16x32_bf16(
                        afrag[mt][s], bfrag[tt], acc[mt][tt], 0, 0, 0);
        }

        // issue second prefetch half (latency hidden under epilogue)
        if (k < 2) { ISSUE(2, d + 1) ISSUE(3, d + 1) }

        // epilogue: attn scattered reads (L1/L2-hot for k>0), inv from LDS
        #pragma unroll
        for (int tt = 0; tt < 4; ++tt) {
            const int n  = tt * 16 + col;
            const int hw = hwbase + n;
            const int p  = hw / 9;
            const int jj = hw - p * 9;
            const int q  = p - p0;
            const int l  = lbase + p;
            const int kidx = ii * 9 + jj;
            #pragma unroll
            for (int mt = 0; mt < 2; ++mt) {
                #pragma unroll
                for (int r = 0; r < 4; ++r) {
                    const int c = wbase + mt * 16 + quad * 4 + r;
                    const float y  = acc[mt][tt][r] + bias[mt][r];
                    const float a  = attn[(size_t)c * DHW + (size_t)l * PP + kidx];
                    const float iv = inv_s[c][q];
                    const float v  = y * (y + a * iv + 1.0f);
                    out[(size_t)c * DHW + (size_t)d * HW + hw] =
                        fmaxf(v, 0.2f * v);
                }
            }
        }

        // convert + publish next tile
        if (k < 2) {
            WRITE(0, nb) WRITE(1, nb) WRITE(2, nb) WRITE(3, nb)
        }
        __syncthreads();
    }
#undef ISSUE
#undef WRITE
}

// ---------------------------------------------------------------------------
// Fallback (known-good) in case ws is too small for inv table.
// ---------------------------------------------------------------------------
__global__ __launch_bounds__(256) void fused_cross_head_fallback(
    const float* __restrict__ x, const float* __restrict__ attn,
    const float* __restrict__ W, const float* __restrict__ bia,
    float* __restrict__ out)
{
    __shared__ __align__(16) short xs[2][48][LDSK];
    __shared__ float inv_lds[COUT][4];

    const int t = threadIdx.x, wv = t >> 6, lane = t & 63;
    const int col = lane & 15, quad = lane >> 4;
    const int blk = blockIdx.x;
    const int pd = blk / 144, hwblk = blk - pd * 144;
    const int hwbase = hwblk * 36;
    const int lbase = pd * NPW + hwblk * 4;

    for (int pair = t; pair < 512; pair += 256) {
        const int c = pair >> 2, p = pair & 3;
        const float* ap = attn + (size_t)c * DHW + (size_t)(lbase + p) * PP;
        int cnt = 0;
        #pragma unroll 27
        for (int q = 0; q < PP; ++q) cnt += (ap[q] != 0.0f) ? 1 : 0;
        inv_lds[c][p] = 1.0f / ((float)cnt + 1e-5f);
    }
    const int wbase = wv * 32;
    bf16x8 afrag[2][4];
    #pragma unroll
    for (int mt = 0; mt < 2; ++mt) {
        const int m = wbase + mt * 16 + col;
        #pragma unroll
        for (int s = 0; s < 4; ++s) {
            const float4* wp4 = (const float4*)(W + m * 128 + s * 32 + quad * 8);
            float4 w0 = wp4[0], w1 = wp4[1];
            bf16x8 f;
            f[0] = f2bf(w0.x); f[1] = f2bf(w0.y); f[2] = f2bf(w0.z); f[3] = f2bf(w0.w);
            f[4] = f2bf(w1.x); f[5] = f2bf(w1.y); f[6] = f2bf(w1.z); f[7] = f2bf(w1.w);
            afrag[mt][s] = f;
        }
    }
    float bias[2][4];
    #pragma unroll
    for (int mt = 0; mt < 2; ++mt)
        #pragma unroll
        for (int r = 0; r < 4; ++r)
            bias[mt][r] = bia[wbase + mt * 16 + quad * 4 + r];

    for (int i = 0; i < 9; ++i) {
        const int buf = i & 1;
        const int d = pd * PATCH + i;
        for (int e = t; e < 1152; e += 256) {
            const int row = e / 9, f4 = e - row * 9;
            const float4 v = *(const float4*)(x + (size_t)row * DHW + (size_t)d * HW
                                              + hwbase + f4 * 4);
            const int n0 = f4 * 4;
            xs[buf][n0 + 0][row] = f2bf(v.x);
            xs[buf][n0 + 1][row] = f2bf(v.y);
            xs[buf][n0 + 2][row] = f2bf(v.z);
            xs[buf][n0 + 3][row] = f2bf(v.w);
        }
        __syncthreads();
        f32x4 acc[2][3];
        #pragma unroll
        for (int mt = 0; mt < 2; ++mt)
            #pragma unroll
            for (int tt = 0; tt < 3; ++tt)
                acc[mt][tt] = (f32x4){0.f, 0.f, 0.f, 0.f};
        #pragma unroll
        for (int s = 0; s < 4; ++s) {
            bf16x8 bfrag[3];
            #pragma unroll
            for (int tt = 0; tt < 3; ++tt)
                bfrag[tt] = *(const bf16x8*)&xs[buf][tt * 16 + col][s * 32 + quad * 8];
            #pragma unroll
            for (int mt = 0; mt < 2; ++mt)
                #pragma unroll
                for (int tt = 0; tt < 3; ++tt)
                    acc[mt][tt] = __builtin_amdgcn_mfma_f32_16x16x32_bf16(
                        afrag[mt][s], bfrag[tt], acc[mt][tt], 0, 0, 0);
        }
        #pragma unroll
        for (int tt = 0; tt < 3; ++tt) {
            const int n = tt * 16 + col;
            if (n < 36) {
                const int p = n / 9, jj = n - p * 9, kk = i * 9 + jj;
                #pragma unroll
                for (int mt = 0; mt < 2; ++mt) {
                    #pragma unroll
                    for (int r = 0; r < 4; ++r) {
                        const int c = wbase + mt * 16 + quad * 4 + r;
                        const float y = acc[mt][tt][r] + bias[mt][r];
                        const float a = attn[(size_t)c * DHW + (size_t)(lbase + p) * PP + kk];
                        const float v = y * (y + a * inv_lds[c][p] + 1.0f);
                        out[(size_t)c * DHW + (size_t)d * HW + hwbase + n] =
                            (v >= 0.f) ? v : 0.2f * v;
                    }
                }
            }
        }
        __syncthreads();
    }
}

extern "C" void kernel_launch(void* const* d_in, const int* in_sizes, int n_in,
                              void* d_out, int out_size, void* d_ws, size_t ws_size,
                              hipStream_t stream) {
    const float* x    = (const float*)d_in[0];
    const float* attn = (const float*)d_in[1];
    const float* W    = (const float*)d_in[2];
    const float* b    = (const float*)d_in[3];
    float* out        = (float*)d_out;

    const size_t inv_bytes = (size_t)COUT * L_TOT * sizeof(float);  // 1.18 MB
    if (ws_size >= inv_bytes) {
        float* inv = (float*)d_ws;
        count_ballot<<<dim3(4608), dim3(256), 0, stream>>>(attn, inv);
        // 972 blocks = 3 d-tiles each; single co-resident generation
        fused_pipe<<<dim3(972), dim3(256), 0, stream>>>(x, attn, W, b, inv, out);
    } else {
        fused_cross_head_fallback<<<dim3(576), dim3(256), 0, stream>>>(x, attn, W, b, out);
    }
}

// Round 5
// 279.840 us; speedup vs baseline: 1.1782x; 1.1782x over previous
//
#include <hip/hip_runtime.h>

// Problem constants
#define CIN   128
#define COUT  128
#define DD    36
#define HW    5184
#define DHW   186624          // 36*5184 ; attn per-channel plane is L*81 = same
#define PATCH 9
#define NPW   576             // patches per d-slab (HW/9)
#define L_TOT 2304            // 4 * 576
#define PP    81
#define LDSK  136             // padded k stride (128 + 8) in bf16 elems

typedef __attribute__((ext_vector_type(8))) short bf16x8;
typedef __attribute__((ext_vector_type(4))) float f32x4;

__device__ __forceinline__ short f2bf(float f) {
    unsigned u = __builtin_bit_cast(unsigned, f);
    unsigned r = (u + 0x7fffu + ((u >> 16) & 1u)) >> 16;
    return (short)r;
}

// async global->LDS DMA, 4B per lane; LDS dest = wave-uniform base + lane*4,
// global src is per-lane (m173). No VGPR round-trip, no serialized waits.
__device__ __forceinline__ void gload_lds4(const float* g, float* l) {
    __builtin_amdgcn_global_load_lds(
        (const __attribute__((address_space(1))) void*)g,
        (__attribute__((address_space(3))) void*)l, 4, 0, 0);
}

// ---------------------------------------------------------------------------
// Kernel 1: nonzero counts via wave ballots (~20us, near streaming floor).
// Also warms L3 with attn for kernel 2.
// ---------------------------------------------------------------------------
__global__ __launch_bounds__(256) void count_ballot(
    const float* __restrict__ attn, float* __restrict__ inv)
{
    const int wv   = threadIdx.x >> 6;
    const int lane = threadIdx.x & 63;
    const int w    = blockIdx.x * 4 + wv;      // wave id 0..18431

    const unsigned long long P0X = (1ull << 21) - 1;
    const unsigned long long P0Y = (1ull << 20) - 1;
    const unsigned long long P1X = ((1ull << 20) - 1) << 21;
    const unsigned long long P1Y = ((1ull << 21) - 1) << 20;
    const unsigned long long P1Z = ((1ull << 20) - 1) << 20;
    const unsigned long long P2X = ((1ull << 20) - 1) << 41;
    const unsigned long long P2Z = ((1ull << 21) - 1) << 40;
    const unsigned long long P2W = ((1ull << 20) - 1) << 40;
    const unsigned long long P3X = 0x7ull << 61;
    const unsigned long long P3W = 0xFull << 60;
    const unsigned long long TL  = (1ull << 17) - 1;

    #pragma unroll
    for (int k = 0; k < 4; ++k) {
        const int g = w * 4 + k;               // 4-patch group 0..73727
        const float4* ap = (const float4*)attn + (size_t)g * 81;
        const float4 va = ap[lane];
        float4 vb = (float4){0.f, 0.f, 0.f, 0.f};
        if (lane < 17) vb = ap[64 + lane];

        const unsigned long long bx = __ballot(va.x != 0.f);
        const unsigned long long by = __ballot(va.y != 0.f);
        const unsigned long long bz = __ballot(va.z != 0.f);
        const unsigned long long bw = __ballot(va.w != 0.f);
        const unsigned long long tx = __ballot(vb.x != 0.f);
        const unsigned long long ty = __ballot(vb.y != 0.f);
        const unsigned long long tz = __ballot(vb.z != 0.f);
        const unsigned long long tw = __ballot(vb.w != 0.f);

        const int c0 = __popcll(bx & P0X) + __popcll(by & P0Y)
                     + __popcll(bz & P0Y) + __popcll(bw & P0Y);
        const int c1 = __popcll(bx & P1X) + __popcll(by & P1Y)
                     + __popcll(bz & P1Z) + __popcll(bw & P1Z);
        const int c2 = __popcll(bx & P2X) + __popcll(by & P2X)
                     + __popcll(bz & P2Z) + __popcll(bw & P2W);
        const int c3 = __popcll(bx & P3X) + __popcll(by & P3X)
                     + __popcll(bz & P3X) + __popcll(bw & P3W)
                     + __popcll(tx & TL) + __popcll(ty & TL)
                     + __popcll(tz & TL) + __popcll(tw & TL);

        if (lane < 4) {
            const int cc = (lane == 0) ? c0 : (lane == 1) ? c1
                         : (lane == 2) ? c2 : c3;
            inv[(size_t)g * 4 + lane] = 1.0f / ((float)cc + 1e-5f);
        }
    }
}

// ---------------------------------------------------------------------------
// Kernel 2: fused 1x1x1-conv GEMM + attention epilogue, v4.
// Identical tiling to v3 (113us, FETCH ~ideal) but ALL scattered staging
// (attn 9216 floats + inv 1024 floats) goes through global_load_lds DMA:
// 40 fire-and-forget issues per wave, ONE drain at the barrier -- replacing
// ~36 serialized VGPR-starved load->convert->ds_write round-trips that made
// each block live ~32us.  launch_bounds(256,2) lets the x-stage's 8 float4
// loads batch fully.
// ---------------------------------------------------------------------------
__global__ __launch_bounds__(256, 2) void fused_main_v4(
    const float* __restrict__ x,     // [128][36][5184]
    const float* __restrict__ attn,  // [128][2304][81]
    const float* __restrict__ W,     // [128][128]
    const float* __restrict__ bia,   // [128]
    const float* __restrict__ inv,   // [128][2304]
    float* __restrict__ out)         // [128][36][5184]
{
    __shared__ __align__(16) short xs[64][LDSK];   // 17408 B, x-tile [n][k]
    __shared__ float attn_f[9216];                 // 36864 B, [c][q*9+j] packed 72/c
    __shared__ float inv_f[1024];                  //  4096 B, [c][q]

    const int t    = threadIdx.x;
    const int wv   = t >> 6;
    const int lane = t & 63;
    const int col  = lane & 15;
    const int quad = lane >> 4;

    // bijective XCD chunk swizzle: nwg=2916, q=364, r=4 (m204 formula)
    const int bidRaw = blockIdx.x;
    const int xcd = bidRaw & 7;
    const int loc = bidRaw >> 3;
    const int wgid = (xcd < 4 ? xcd * 365 : 1460 + (xcd - 4) * 364) + loc;

    const int d      = wgid % 36;             // fastest: d-neighbors share attn lines
    const int hwblk  = wgid / 36;             // 0..80
    const int hwbase = hwblk * 64;
    const int lbase  = (d / 9) * NPW;
    const int ii     = d % 9;                 // kernel-row index within patch
    const int p0     = hwbase / 9;            // 8 patches q=0..7 touched
    const int lp0    = lbase + p0;
    const int iioff  = ii * 9;

    // ---- x loads (register route; 8 independent float4, fully batched) ----
    float4 pva[4], pvb[4];
    #pragma unroll
    for (int it = 0; it < 4; ++it) {
        const int e  = t + 256 * it;          // 0..1023
        const int rp = e >> 4, f4 = e & 15;
        const float* xp = x + (size_t)(rp * 2) * DHW + (size_t)d * HW
                        + hwbase + f4 * 4;
        pva[it] = *(const float4*)xp;
        pvb[it] = *(const float4*)(xp + DHW);
    }

    // ---- attn DMA: 9216 floats, 36 issues/wave, zero VGPR round-trip ----
    {
        const int wbE = wv * 64;
        #pragma unroll
        for (int k = 0; k < 36; ++k) {
            const int e   = k * 256 + wbE + lane;  // flat idx 0..9215
            const int c   = e / 72;
            const int rem = e - c * 72;            // q*9 + j
            const int q   = rem / 9;
            const int j   = rem - q * 9;
            const float* g = attn + (size_t)c * DHW + (size_t)(lp0 + q) * PP
                           + iioff + j;
            gload_lds4(g, &attn_f[k * 256 + wbE]);
        }
        // ---- inv DMA: 1024 floats, 4 issues/wave ----
        #pragma unroll
        for (int k = 0; k < 4; ++k) {
            const int e = k * 256 + wbE + lane;    // 0..1023
            const int c = e >> 3, q = e & 7;
            const float* g = inv + (size_t)c * L_TOT + lp0 + q;
            gload_lds4(g, &inv_f[k * 256 + wbE]);
        }
    }

    // ---- A fragments: W rows for this wave (Cout tile = wv*32 .. +32) ----
    const int wbase = wv * 32;
    bf16x8 afrag[2][4];
    #pragma unroll
    for (int mt = 0; mt < 2; ++mt) {
        const int m = wbase + mt * 16 + col;
        #pragma unroll
        for (int s = 0; s < 4; ++s) {
            const float4* wp4 = (const float4*)(W + m * 128 + s * 32 + quad * 8);
            float4 w0 = wp4[0], w1 = wp4[1];
            bf16x8 f;
            f[0] = f2bf(w0.x); f[1] = f2bf(w0.y); f[2] = f2bf(w0.z); f[3] = f2bf(w0.w);
            f[4] = f2bf(w1.x); f[5] = f2bf(w1.y); f[6] = f2bf(w1.z); f[7] = f2bf(w1.w);
            afrag[mt][s] = f;
        }
    }
    float bias[2][4];
    #pragma unroll
    for (int mt = 0; mt < 2; ++mt)
        #pragma unroll
        for (int r = 0; r < 4; ++r)
            bias[mt][r] = bia[wbase + mt * 16 + quad * 4 + r];

    // ---- convert + LDS-write x tile (DMA still in flight underneath) ----
    #pragma unroll
    for (int it = 0; it < 4; ++it) {
        const int e  = t + 256 * it;
        const int rp = e >> 4, f4 = e & 15;
        const int row = rp * 2, n0 = f4 * 4;
        const float4 va = pva[it], vb = pvb[it];
        *(unsigned*)&xs[n0 + 0][row] =
            (unsigned)(unsigned short)f2bf(va.x) | ((unsigned)(unsigned short)f2bf(vb.x) << 16);
        *(unsigned*)&xs[n0 + 1][row] =
            (unsigned)(unsigned short)f2bf(va.y) | ((unsigned)(unsigned short)f2bf(vb.y) << 16);
        *(unsigned*)&xs[n0 + 2][row] =
            (unsigned)(unsigned short)f2bf(va.z) | ((unsigned)(unsigned short)f2bf(vb.z) << 16);
        *(unsigned*)&xs[n0 + 3][row] =
            (unsigned)(unsigned short)f2bf(va.w) | ((unsigned)(unsigned short)f2bf(vb.w) << 16);
    }

    __syncthreads();   // drains lgkmcnt (ds_write) + vmcnt (DMA) once

    // ---- GEMM: 128(Cout) x 64(n) x 128(K), 16x16x32 MFMA ----
    f32x4 acc[2][4];
    #pragma unroll
    for (int mt = 0; mt < 2; ++mt)
        #pragma unroll
        for (int tt = 0; tt < 4; ++tt)
            acc[mt][tt] = (f32x4){0.f, 0.f, 0.f, 0.f};

    #pragma unroll
    for (int s = 0; s < 4; ++s) {
        bf16x8 bfrag[4];
        #pragma unroll
        for (int tt = 0; tt < 4; ++tt)
            bfrag[tt] = *(const bf16x8*)&xs[tt * 16 + col][s * 32 + quad * 8];
        #pragma unroll
        for (int mt = 0; mt < 2; ++mt)
            #pragma unroll
            for (int tt = 0; tt < 4; ++tt)
                acc[mt][tt] = __builtin_amdgcn_mfma_f32_16x16x32_bf16(
                    afrag[mt][s], bfrag[tt], acc[mt][tt], 0, 0, 0);
    }

    // ---- epilogue: attn/inv from LDS (fp32); coalesced full-line stores ----
    #pragma unroll
    for (int tt = 0; tt < 4; ++tt) {
        const int n  = tt * 16 + col;
        const int hw = hwbase + n;
        const int p  = hw / 9;
        const int jj = hw - p * 9;
        const int q  = p - p0;                // 0..7
        const int rem = q * 9 + jj;
        #pragma unroll
        for (int mt = 0; mt < 2; ++mt) {
            #pragma unroll
            for (int r = 0; r < 4; ++r) {
                const int c = wbase + mt * 16 + quad * 4 + r;
                const float y  = acc[mt][tt][r] + bias[mt][r];
                const float a  = attn_f[c * 72 + rem];
                const float iv = inv_f[c * 8 + q];
                const float v  = y * (y + a * iv + 1.0f);
                out[(size_t)c * DHW + (size_t)d * HW + hw] =
                    (v >= 0.f) ? v : 0.2f * v;
            }
        }
    }
}

// ---------------------------------------------------------------------------
// Fallback (known-good) in case ws is too small for inv table.
// ---------------------------------------------------------------------------
__global__ __launch_bounds__(256) void fused_cross_head_fallback(
    const float* __restrict__ x, const float* __restrict__ attn,
    const float* __restrict__ W, const float* __restrict__ bia,
    float* __restrict__ out)
{
    __shared__ __align__(16) short xs[2][48][LDSK];
    __shared__ float inv_lds[COUT][4];

    const int t = threadIdx.x, wv = t >> 6, lane = t & 63;
    const int col = lane & 15, quad = lane >> 4;
    const int blk = blockIdx.x;
    const int pd = blk / 144, hwblk = blk - pd * 144;
    const int hwbase = hwblk * 36;
    const int lbase = pd * NPW + hwblk * 4;

    for (int pair = t; pair < 512; pair += 256) {
        const int c = pair >> 2, p = pair & 3;
        const float* ap = attn + (size_t)c * DHW + (size_t)(lbase + p) * PP;
        int cnt = 0;
        #pragma unroll 27
        for (int q = 0; q < PP; ++q) cnt += (ap[q] != 0.0f) ? 1 : 0;
        inv_lds[c][p] = 1.0f / ((float)cnt + 1e-5f);
    }
    const int wbase = wv * 32;
    bf16x8 afrag[2][4];
    #pragma unroll
    for (int mt = 0; mt < 2; ++mt) {
        const int m = wbase + mt * 16 + col;
        #pragma unroll
        for (int s = 0; s < 4; ++s) {
            const float4* wp4 = (const float4*)(W + m * 128 + s * 32 + quad * 8);
            float4 w0 = wp4[0], w1 = wp4[1];
            bf16x8 f;
            f[0] = f2bf(w0.x); f[1] = f2bf(w0.y); f[2] = f2bf(w0.z); f[3] = f2bf(w0.w);
            f[4] = f2bf(w1.x); f[5] = f2bf(w1.y); f[6] = f2bf(w1.z); f[7] = f2bf(w1.w);
            afrag[mt][s] = f;
        }
    }
    float bias[2][4];
    #pragma unroll
    for (int mt = 0; mt < 2; ++mt)
        #pragma unroll
        for (int r = 0; r < 4; ++r)
            bias[mt][r] = bia[wbase + mt * 16 + quad * 4 + r];

    for (int i = 0; i < 9; ++i) {
        const int buf = i & 1;
        const int d = pd * PATCH + i;
        for (int e = t; e < 1152; e += 256) {
            const int row = e / 9, f4 = e - row * 9;
            const float4 v = *(const float4*)(x + (size_t)row * DHW + (size_t)d * HW
                                              + hwbase + f4 * 4);
            const int n0 = f4 * 4;
            xs[buf][n0 + 0][row] = f2bf(v.x);
            xs[buf][n0 + 1][row] = f2bf(v.y);
            xs[buf][n0 + 2][row] = f2bf(v.z);
            xs[buf][n0 + 3][row] = f2bf(v.w);
        }
        __syncthreads();
        f32x4 acc[2][3];
        #pragma unroll
        for (int mt = 0; mt < 2; ++mt)
            #pragma unroll
            for (int tt = 0; tt < 3; ++tt)
                acc[mt][tt] = (f32x4){0.f, 0.f, 0.f, 0.f};
        #pragma unroll
        for (int s = 0; s < 4; ++s) {
            bf16x8 bfrag[3];
            #pragma unroll
            for (int tt = 0; tt < 3; ++tt)
                bfrag[tt] = *(const bf16x8*)&xs[buf][tt * 16 + col][s * 32 + quad * 8];
            #pragma unroll
            for (int mt = 0; mt < 2; ++mt)
                #pragma unroll
                for (int tt = 0; tt < 3; ++tt)
                    acc[mt][tt] = __builtin_amdgcn_mfma_f32_16x16x32_bf16(
                        afrag[mt][s], bfrag[tt], acc[mt][tt], 0, 0, 0);
        }
        #pragma unroll
        for (int tt = 0; tt < 3; ++tt) {
            const int n = tt * 16 + col;
            if (n < 36) {
                const int p = n / 9, jj = n - p * 9, kk = i * 9 + jj;
                #pragma unroll
                for (int mt = 0; mt < 2; ++mt) {
                    #pragma unroll
                    for (int r = 0; r < 4; ++r) {
                        const int c = wbase + mt * 16 + quad * 4 + r;
                        const float y = acc[mt][tt][r] + bias[mt][r];
                        const float a = attn[(size_t)c * DHW + (size_t)(lbase + p) * PP + kk];
                        const float v = y * (y + a * inv_lds[c][p] + 1.0f);
                        out[(size_t)c * DHW + (size_t)d * HW + hwbase + n] =
                            (v >= 0.f) ? v : 0.2f * v;
                    }
                }
            }
        }
        __syncthreads();
    }
}

extern "C" void kernel_launch(void* const* d_in, const int* in_sizes, int n_in,
                              void* d_out, int out_size, void* d_ws, size_t ws_size,
                              hipStream_t stream) {
    const float* x    = (const float*)d_in[0];
    const float* attn = (const float*)d_in[1];
    const float* W    = (const float*)d_in[2];
    const float* b    = (const float*)d_in[3];
    float* out        = (float*)d_out;

    const size_t inv_bytes = (size_t)COUT * L_TOT * sizeof(float);  // 1.18 MB
    if (ws_size >= inv_bytes) {
        float* inv = (float*)d_ws;
        count_ballot<<<dim3(4608), dim3(256), 0, stream>>>(attn, inv);
        fused_main_v4<<<dim3(36 * 81), dim3(256), 0, stream>>>(x, attn, W, b, inv, out);
    } else {
        fused_cross_head_fallback<<<dim3(576), dim3(256), 0, stream>>>(x, attn, W, b, out);
    }
}